// Round 9
// baseline (129.915 us; speedup 1.0000x reference)
//
#include <hip/hip_runtime.h>

// Problem: B=4, H=16, S=2048, D=64
//   scores = Q K^T / 8 ; attn = tanh(0.3*scores) ; out = attn V   (mask unused)
// Round 9: EXACTLY R4 (best, 104.8us) with tanh swapped to Pade[5/4]
//   (proven numerically in R5: absmax 0.5). Halves trans ops (exp2+rcp ->
//   rcp only); numerator/denominator are pk-able FMAs.
//   R8's Taylor poly failed because sacc is the RAW dot product (std=8,
//   tails to ~60) — y=0.0375*s reaches ~2.3 where Taylor diverges. Pade[5/4]
//   is ~1e-4 accurate on |y|<=2.5 and clamped beyond.

constexpr int S_LEN = 2048;
constexpr int DIM   = 64;
constexpr int QT    = 256;
constexpr int KT    = 64;
constexpr int NKT   = S_LEN / KT;   // 32

typedef __bf16 bf16_t;
typedef bf16_t bf16x4 __attribute__((ext_vector_type(4)));
typedef bf16_t bf16x8 __attribute__((ext_vector_type(8)));
typedef float  f32x4  __attribute__((ext_vector_type(4)));

__device__ inline bf16x8 to_bf8(float4 a, float4 b) {
    bf16x8 v;
    v[0] = (bf16_t)a.x; v[1] = (bf16_t)a.y; v[2] = (bf16_t)a.z; v[3] = (bf16_t)a.w;
    v[4] = (bf16_t)b.x; v[5] = (bf16_t)b.y; v[6] = (bf16_t)b.z; v[7] = (bf16_t)b.w;
    return v;
}

// tanh(T*s), T=0.0375, via Pade[5/4] in y=T*s:
//   tanh(y) ~= y*(945 + 105 y^2 + y^4) / (945 + 420 y^2 + 15 y^4)
// folded into w = s*s. Max abs err ~1e-4 for |y|<=2.5; clamped beyond.
// (R5 shipped these semantics and passed with absmax 0.5.)
__device__ inline f32x4 tanh_pade4(f32x4 s) {
    const float T  = 0.0375f;
    const float a1 = 0.14765625f;         // 105*T^2
    const float a2 = 1.9775390625e-6f;    // T^4
    const float b1 = 0.590625f;           // 420*T^2
    const float b2 = 2.96630859375e-5f;   // 15*T^4
    f32x4 w = s * s;
    f32x4 num = (w * a2 + a1) * w + 945.0f;
    f32x4 den = (w * b2 + b1) * w + 945.0f;
    f32x4 r;
    #pragma unroll
    for (int j = 0; j < 4; ++j) r[j] = __builtin_amdgcn_rcpf(den[j]);
    r = (s * T) * num * r;
    r = __builtin_elementwise_min(r, f32x4{1.f, 1.f, 1.f, 1.f});
    r = __builtin_elementwise_max(r, f32x4{-1.f, -1.f, -1.f, -1.f});
    return r;
}

__global__ __launch_bounds__(512, 4) void tanh_attn_kernel(
    const float* __restrict__ Q, const float* __restrict__ K,
    const float* __restrict__ V, float* __restrict__ O)
{
    const int tid  = threadIdx.x;
    const int lane = tid & 63;
    const int wv   = tid >> 6;          // wave id 0..7 (32 q-rows each)
    const int lr   = lane & 15;
    const int lg   = lane >> 4;

    // XCD-aware bijective swizzle (grid=512, 512%8==0)
    const int nwg = gridDim.x;
    const int bid = (blockIdx.x & 7) * (nwg >> 3) + (blockIdx.x >> 3);
    const int qtile = bid & 7;          // S/QT = 8
    const int bh    = bid >> 3;         // 0..63
    const int base  = bh * (S_LEN * DIM);
    const int q0    = qtile * QT;

    __shared__ bf16_t Ql[QT * DIM];     // 32 KB (Q frags; reused as per-wave P)
    __shared__ bf16_t Kl[2][KT * DIM];  // 2 x 8 KB, [kv][d] swizzled
    __shared__ bf16_t Vt[2][DIM * KT];  // 2 x 8 KB, [d][kv] swizzled (V^T)

    const float* Kb = K + base;
    const float* Vb = V + base;

    // fixed per-thread staging map
    const int sr  = tid >> 3;           // K row 0..63
    const int sc8 = (tid & 7) * 8;      // K col chunk
    const int sd  = tid & 63;           // V d column
    const int skv = (tid >> 6) * 8;     // V kv chunk base

    // ---- issue tile-0 prefetch first (latency overlaps Q staging) ----
    float4 ka, kb2;
    float  vv[8];
    {
        const float* src = Kb + sr * DIM + sc8;
        ka  = *(const float4*)src;
        kb2 = *(const float4*)(src + 4);
        const float* vsrc = Vb + skv * DIM + sd;
        #pragma unroll
        for (int j = 0; j < 8; ++j) vv[j] = vsrc[j * DIM];
    }

    // ---- stage Q tile (f32 -> bf16, XOR swizzle (row&7)<<3) ----
    #pragma unroll
    for (int it = 0; it < 4; ++it) {
        int cid = tid + it * 512;           // 0..2047
        int r   = cid >> 3;
        int c8  = (cid & 7) * 8;
        const float* src = Q + base + (q0 + r) * DIM + c8;
        float4 a = *(const float4*)src;
        float4 b = *(const float4*)(src + 4);
        *(bf16x8*)&Ql[r * DIM + (c8 ^ ((r & 7) << 3))] = to_bf8(a, b);
    }
    __syncthreads();

    // ---- hoist Q fragments (wave's own 32 rows; its P slice = same region,
    //      so no further barrier needed) ----
    bf16x8 qa[2][2];
    #pragma unroll
    for (int rt = 0; rt < 2; ++rt)
        #pragma unroll
        for (int ks = 0; ks < 2; ++ks) {
            int r = wv * 32 + rt * 16 + lr;
            int c = ks * 32 + lg * 8;
            qa[rt][ks] = *(const bf16x8*)&Ql[r * DIM + (c ^ ((r & 7) << 3))];
        }

    // ---- write tile 0 into buffer 0 ----
    {
        *(bf16x8*)&Kl[0][sr * DIM + (sc8 ^ ((sr & 7) << 3))] = to_bf8(ka, kb2);
        bf16x8 v;
        #pragma unroll
        for (int j = 0; j < 8; ++j) v[j] = (bf16_t)vv[j];
        *(bf16x8*)&Vt[0][sd * KT + (skv ^ ((sd & 7) << 3))] = v;
    }

    f32x4 oacc[2][4] = {};
    bf16_t* Pl = Ql + wv * (32 * KT);   // per-wave P slice [32][64] swizzled

    #pragma unroll 2
    for (int kt = 0; kt < NKT; ++kt) {
        const int cur = kt & 1;

        // ONE barrier per tile: publishes buf[cur] writes (end of kt-1) and
        // proves all waves finished reading buf[cur^1].
        __syncthreads();

        // next-tile global loads issued AFTER the barrier; land during compute
        if (kt + 1 < NKT) {
            const int k0n = (kt + 1) * KT;
            const float* src = Kb + (k0n + sr) * DIM + sc8;
            ka  = *(const float4*)src;
            kb2 = *(const float4*)(src + 4);
            const float* vsrc = Vb + (k0n + skv) * DIM + sd;
            #pragma unroll
            for (int j = 0; j < 8; ++j) vv[j] = vsrc[j * DIM];
        }

        const bf16_t* Kc = Kl[cur];
        const bf16_t* Vc = Vt[cur];

        // ---- GEMM1 (swapped): S^T = K · Q^T; D[m=kv][n=q] ----
        f32x4 sacc[2][4] = {};
        __builtin_amdgcn_s_setprio(1);
        #pragma unroll
        for (int ct = 0; ct < 4; ++ct) {
            int r = ct * 16 + lr;           // kv
            bf16x8 kf0 = *(const bf16x8*)&Kc[r * DIM + ((lg * 8)      ^ ((r & 7) << 3))];
            bf16x8 kf1 = *(const bf16x8*)&Kc[r * DIM + ((32 + lg * 8) ^ ((r & 7) << 3))];
            #pragma unroll
            for (int rt = 0; rt < 2; ++rt) {
                sacc[rt][ct] = __builtin_amdgcn_mfma_f32_16x16x32_bf16(kf0, qa[rt][0], sacc[rt][ct], 0, 0, 0);
                sacc[rt][ct] = __builtin_amdgcn_mfma_f32_16x16x32_bf16(kf1, qa[rt][1], sacc[rt][ct], 0, 0, 0);
            }
        }
        __builtin_amdgcn_s_setprio(0);

        // ---- Pade tanh (1 trans op per element) + packed P store ----
        // lane holds q=rt*16+lr, kv=ct*16+lg*4+j
        #pragma unroll
        for (int rt = 0; rt < 2; ++rt)
            #pragma unroll
            for (int ct = 0; ct < 4; ++ct) {
                f32x4 p = tanh_pade4(sacc[rt][ct]);
                bf16x4 p4;
                #pragma unroll
                for (int j = 0; j < 4; ++j) p4[j] = (bf16_t)p[j];
                int q  = rt * 16 + lr;
                int c0 = ct * 16 + lg * 4;
                *(bf16x4*)&Pl[q * KT + (c0 ^ ((q & 7) << 3))] = p4;
            }

        // ---- P A-fragments (same-wave LDS slice, no barrier) ----
        bf16x8 pa[2][2];
        #pragma unroll
        for (int rt = 0; rt < 2; ++rt)
            #pragma unroll
            for (int ks = 0; ks < 2; ++ks) {
                int r = rt * 16 + lr;
                pa[rt][ks] = *(const bf16x8*)&Pl[r * KT + ((ks * 32 + lg * 8) ^ ((r & 7) << 3))];
            }

        // ---- GEMM2: O += P · V ----
        __builtin_amdgcn_s_setprio(1);
        #pragma unroll
        for (int dt = 0; dt < 4; ++dt) {
            int d = dt * 16 + lr;
            bf16x8 vf0 = *(const bf16x8*)&Vc[d * KT + ((lg * 8)      ^ ((d & 7) << 3))];
            bf16x8 vf1 = *(const bf16x8*)&Vc[d * KT + ((32 + lg * 8) ^ ((d & 7) << 3))];
            #pragma unroll
            for (int rt = 0; rt < 2; ++rt) {
                oacc[rt][dt] = __builtin_amdgcn_mfma_f32_16x16x32_bf16(pa[rt][0], vf0, oacc[rt][dt], 0, 0, 0);
                oacc[rt][dt] = __builtin_amdgcn_mfma_f32_16x16x32_bf16(pa[rt][1], vf1, oacc[rt][dt], 0, 0, 0);
            }
        }
        __builtin_amdgcn_s_setprio(0);

        // ---- write next tile into the other buffer (loads landed during
        //      compute; next barrier publishes these writes) ----
        if (kt + 1 < NKT) {
            const int nxt = cur ^ 1;
            *(bf16x8*)&Kl[nxt][sr * DIM + (sc8 ^ ((sr & 7) << 3))] = to_bf8(ka, kb2);
            bf16x8 v;
            #pragma unroll
            for (int j = 0; j < 8; ++j) v[j] = (bf16_t)vv[j];
            *(bf16x8*)&Vt[nxt][sd * KT + (skv ^ ((sd & 7) << 3))] = v;
        }
    }

    // ---- epilogue: write O (f32) ----
    #pragma unroll
    for (int rt = 0; rt < 2; ++rt)
        #pragma unroll
        for (int dt = 0; dt < 4; ++dt)
            #pragma unroll
            for (int j = 0; j < 4; ++j) {
                int q = q0 + wv * 32 + rt * 16 + lg * 4 + j;
                int d = dt * 16 + lr;
                O[base + q * DIM + d] = oacc[rt][dt][j];
            }
}

extern "C" void kernel_launch(void* const* d_in, const int* in_sizes, int n_in,
                              void* d_out, int out_size, void* d_ws, size_t ws_size,
                              hipStream_t stream) {
    const float* Q = (const float*)d_in[0];
    const float* K = (const float*)d_in[1];
    const float* V = (const float*)d_in[2];
    float* O = (float*)d_out;
    dim3 grid(64 * (S_LEN / QT));   // 512 blocks
    dim3 block(512);
    hipLaunchKernelGGL(tanh_attn_kernel, grid, block, 0, stream, Q, K, V, O);
}

// Round 10
// 128.109 us; speedup vs baseline: 1.0141x; 1.0141x over previous
//
#include <hip/hip_runtime.h>

// Problem: B=4, H=16, S=2048, D=64
//   scores = Q K^T / 8 ; attn = tanh(0.3*scores) ; out = attn V   (mask unused)
// Round 10: wave-group ANTI-PHASING. Evidence R3..R9: wall = sum of
//   lockstep per-CU phase windows (frag-LDS | tanh | P | V+G2). Split waves:
//   A (wv<4): G1(p) -> tanh(p) -> G2(p)
//   B (wv>=4): tanh(p-1) -> G2(p-1) [sacc carried] -> G1(p)
//   so A's VALU/trans window overlaps B's LDS/MFMA window. V tri-buffered,
//   K double-buffered, Q direct-from-global, P in-register (R6 permlane).

constexpr int S_LEN = 2048;
constexpr int DIM   = 64;
constexpr int QT    = 256;
constexpr int KT    = 64;
constexpr int NKT   = S_LEN / KT;   // 32

// tanh(a*x) = 1 - 2/(exp2(2*a*x*log2e)+1); a = 0.3/8 = 0.0375
constexpr float C_EXP2 = 0.10820212528f;

typedef __bf16 bf16_t;
typedef bf16_t bf16x8 __attribute__((ext_vector_type(8)));
typedef float  f32x4  __attribute__((ext_vector_type(4)));

typedef f32x4 sacc_t[2][4];
typedef bf16x8 pa_t[2][2];

__device__ inline bf16x8 to_bf8(float4 a, float4 b) {
    bf16x8 v;
    v[0] = (bf16_t)a.x; v[1] = (bf16_t)a.y; v[2] = (bf16_t)a.z; v[3] = (bf16_t)a.w;
    v[4] = (bf16_t)b.x; v[5] = (bf16_t)b.y; v[6] = (bf16_t)b.z; v[7] = (bf16_t)b.w;
    return v;
}

__device__ inline float tanh_fast(float s) {
    float t = __builtin_amdgcn_exp2f(s * C_EXP2);
    return 1.0f - 2.0f * __builtin_amdgcn_rcpf(t + 1.0f);
}

__device__ inline unsigned pack2_bf16(float p0, float p1) {
    union { bf16_t h[2]; unsigned u; } pk;
    pk.h[0] = (bf16_t)p0; pk.h[1] = (bf16_t)p1;
    return pk.u;
}

__device__ inline void permlane32_swap(unsigned &a, unsigned &b) {
    asm("v_permlane32_swap_b32 %0, %1" : "+v"(a), "+v"(b));
}
__device__ inline void permlane16_swap(unsigned &a, unsigned &b) {
    asm("v_permlane16_swap_b32 %0, %1" : "+v"(a), "+v"(b));
}

// GEMM1 (swapped): S^T = K · Q^T over one K-tile; D[m=kv][n=q]
__device__ __forceinline__ void gemm1(const bf16_t* __restrict__ Kc,
                                      const bf16x8 (&qa)[2][2],
                                      sacc_t& sacc, int lr, int lg) {
    #pragma unroll
    for (int rt = 0; rt < 2; ++rt)
        #pragma unroll
        for (int ct = 0; ct < 4; ++ct)
            sacc[rt][ct] = f32x4{0.f, 0.f, 0.f, 0.f};
    __builtin_amdgcn_s_setprio(1);
    #pragma unroll
    for (int ct = 0; ct < 4; ++ct) {
        int r = ct * 16 + lr;           // kv
        bf16x8 kf0 = *(const bf16x8*)&Kc[r * DIM + ((lg * 8)      ^ ((r & 7) << 3))];
        bf16x8 kf1 = *(const bf16x8*)&Kc[r * DIM + ((32 + lg * 8) ^ ((r & 7) << 3))];
        #pragma unroll
        for (int rt = 0; rt < 2; ++rt) {
            sacc[rt][ct] = __builtin_amdgcn_mfma_f32_16x16x32_bf16(kf0, qa[rt][0], sacc[rt][ct], 0, 0, 0);
            sacc[rt][ct] = __builtin_amdgcn_mfma_f32_16x16x32_bf16(kf1, qa[rt][1], sacc[rt][ct], 0, 0, 0);
        }
    }
    __builtin_amdgcn_s_setprio(0);
}

// tanh + in-register P redistribution (validated R5/R6/R7, absmax 0.5)
__device__ __forceinline__ void tanh_redist(const sacc_t& sacc, pa_t& pa) {
    #pragma unroll
    for (int rt = 0; rt < 2; ++rt) {
        unsigned dm[4][2];
        #pragma unroll
        for (int ct = 0; ct < 4; ++ct) {
            dm[ct][0] = pack2_bf16(tanh_fast(sacc[rt][ct][0]),
                                   tanh_fast(sacc[rt][ct][1]));
            dm[ct][1] = pack2_bf16(tanh_fast(sacc[rt][ct][2]),
                                   tanh_fast(sacc[rt][ct][3]));
        }
        #pragma unroll
        for (int ks = 0; ks < 2; ++ks) {
            union { unsigned u[4]; bf16x8 v; } pw;
            #pragma unroll
            for (int jj = 0; jj < 2; ++jj) {
                unsigned A = dm[2 * ks][jj];
                unsigned B = dm[2 * ks + 1][jj];
                permlane32_swap(A, B);
                permlane16_swap(A, B);
                pw.u[jj]     = A;
                pw.u[2 + jj] = B;
            }
            pa[rt][ks] = pw.v;
        }
    }
}

// GEMM2: O += P · V over one K-tile
__device__ __forceinline__ void gemm2(const bf16_t* __restrict__ Vc,
                                      const pa_t& pa, f32x4 (&oacc)[2][4],
                                      int lr, int lg) {
    __builtin_amdgcn_s_setprio(1);
    #pragma unroll
    for (int dt = 0; dt < 4; ++dt) {
        int d = dt * 16 + lr;
        bf16x8 vf0 = *(const bf16x8*)&Vc[d * KT + ((lg * 8)      ^ ((d & 7) << 3))];
        bf16x8 vf1 = *(const bf16x8*)&Vc[d * KT + ((32 + lg * 8) ^ ((d & 7) << 3))];
        #pragma unroll
        for (int rt = 0; rt < 2; ++rt) {
            oacc[rt][dt] = __builtin_amdgcn_mfma_f32_16x16x32_bf16(pa[rt][0], vf0, oacc[rt][dt], 0, 0, 0);
            oacc[rt][dt] = __builtin_amdgcn_mfma_f32_16x16x32_bf16(pa[rt][1], vf1, oacc[rt][dt], 0, 0, 0);
        }
    }
    __builtin_amdgcn_s_setprio(0);
}

__global__ __launch_bounds__(512, 4) void tanh_attn_kernel(
    const float* __restrict__ Q, const float* __restrict__ K,
    const float* __restrict__ V, float* __restrict__ O)
{
    const int tid  = threadIdx.x;
    const int lane = tid & 63;
    const int wv   = tid >> 6;          // 0..7; A group: wv<4, B group: wv>=4
    const int lr   = lane & 15;
    const int lg   = lane >> 4;

    // XCD-aware bijective swizzle (grid=512); same-head blocks share an XCD
    const int nwg = gridDim.x;
    const int bid = (blockIdx.x & 7) * (nwg >> 3) + (blockIdx.x >> 3);
    const int qtile = bid & 7;          // S/QT = 8
    const int bh    = bid >> 3;         // 0..63
    const int base  = bh * (S_LEN * DIM);
    const int q0    = qtile * QT;

    __shared__ bf16_t Kl[2][KT * DIM];  // 2 x 8 KB, [kv][d] swizzled
    __shared__ bf16_t Vt[3][DIM * KT];  // 3 x 8 KB, [d][kv] swizzled (V^T)

    const float* Kb = K + base;
    const float* Vb = V + base;

    // fixed per-thread staging map
    const int sr  = tid >> 3;           // K row 0..63
    const int sc8 = (tid & 7) * 8;      // K col chunk
    const int sd  = tid & 63;           // V d column
    const int skv = (tid >> 6) * 8;     // V kv chunk base

    // ---- issue tile-0 staging loads ----
    float4 ka, kb2;
    float  vv[8];
    {
        const float* src = Kb + sr * DIM + sc8;
        ka  = *(const float4*)src;
        kb2 = *(const float4*)(src + 4);
        const float* vsrc = Vb + skv * DIM + sd;
        #pragma unroll
        for (int j = 0; j < 8; ++j) vv[j] = vsrc[j * DIM];
    }

    // ---- Q fragments direct from global (f32 -> bf16), one-time ----
    bf16x8 qa[2][2];
    #pragma unroll
    for (int rt = 0; rt < 2; ++rt)
        #pragma unroll
        for (int ks = 0; ks < 2; ++ks) {
            const float* src = Q + base + (q0 + wv * 32 + rt * 16 + lr) * DIM
                               + ks * 32 + lg * 8;
            float4 a = *(const float4*)src;
            float4 b = *(const float4*)(src + 4);
            qa[rt][ks] = to_bf8(a, b);
        }

    // ---- write tile 0 into buffers ----
    {
        *(bf16x8*)&Kl[0][sr * DIM + (sc8 ^ ((sr & 7) << 3))] = to_bf8(ka, kb2);
        bf16x8 v;
        #pragma unroll
        for (int j = 0; j < 8; ++j) v[j] = (bf16_t)vv[j];
        *(bf16x8*)&Vt[0][sd * KT + (skv ^ ((sd & 7) << 3))] = v;
    }
    __syncthreads();

    f32x4 oacc[2][4] = {};
    sacc_t sacc;                         // B carries this across periods
    pa_t pa;

    int vCur = 0;                        // Vt index of tile p

    for (int p = 0; p < NKT + 1; ++p) {
        const int vPrev = (vCur == 0) ? 2 : vCur - 1;   // tile p-1
        const int vNext = (vCur == 2) ? 0 : vCur + 1;   // tile p+1

        // issue staging loads for tile p+1 (land during compute)
        if (p + 1 < NKT) {
            const int k0n = (p + 1) * KT;
            const float* src = Kb + (k0n + sr) * DIM + sc8;
            ka  = *(const float4*)src;
            kb2 = *(const float4*)(src + 4);
            const float* vsrc = Vb + (k0n + skv) * DIM + sd;
            #pragma unroll
            for (int j = 0; j < 8; ++j) vv[j] = vsrc[j * DIM];
        }

        if (wv < 4) {
            // ---- A group: full pipeline on tile p ----
            if (p < NKT) {
                gemm1(Kl[p & 1], qa, sacc, lr, lg);
                tanh_redist(sacc, pa);
                gemm2(Vt[vCur], pa, oacc, lr, lg);
            }
        } else {
            // ---- B group: finish tile p-1 (anti-phase), then start tile p ----
            if (p >= 1) {
                tanh_redist(sacc, pa);               // sacc from last period
                gemm2(Vt[vPrev], pa, oacc, lr, lg);
            }
            if (p < NKT) {
                gemm1(Kl[p & 1], qa, sacc, lr, lg);  // deferred finish
            }
        }

        // staging writes for tile p+1 (nobody reads these buffers this period)
        if (p + 1 < NKT) {
            *(bf16x8*)&Kl[(p + 1) & 1][sr * DIM + (sc8 ^ ((sr & 7) << 3))] = to_bf8(ka, kb2);
            bf16x8 v;
            #pragma unroll
            for (int j = 0; j < 8; ++j) v[j] = (bf16_t)vv[j];
            *(bf16x8*)&Vt[vNext][sd * KT + (skv ^ ((sd & 7) << 3))] = v;
        }
        __syncthreads();
        vCur = vNext;
    }

    // ---- epilogue: write O (f32) ----
    #pragma unroll
    for (int rt = 0; rt < 2; ++rt)
        #pragma unroll
        for (int dt = 0; dt < 4; ++dt)
            #pragma unroll
            for (int j = 0; j < 4; ++j) {
                int q = q0 + wv * 32 + rt * 16 + lg * 4 + j;
                int d = dt * 16 + lr;
                O[base + q * DIM + d] = oacc[rt][dt][j];
            }
}

extern "C" void kernel_launch(void* const* d_in, const int* in_sizes, int n_in,
                              void* d_out, int out_size, void* d_ws, size_t ws_size,
                              hipStream_t stream) {
    const float* Q = (const float*)d_in[0];
    const float* K = (const float*)d_in[1];
    const float* V = (const float*)d_in[2];
    float* O = (float*)d_out;
    dim3 grid(64 * (S_LEN / QT));   // 512 blocks
    dim3 block(512);
    hipLaunchKernelGGL(tanh_attn_kernel, grid, block, 0, stream, Q, K, V, O);
}

// Round 11
// 109.236 us; speedup vs baseline: 1.1893x; 1.1728x over previous
//
#include <hip/hip_runtime.h>

// Problem: B=4, H=16, S=2048, D=64
//   scores = Q K^T / 8 ; attn = tanh(0.3*scores) ; out = attn V   (mask unused)
// Round 11: R4 (champion, 104.8us) with ONLY the tanh+P-convert block
//   rewritten in packed-f32x2 form: v_pk_mul/add/fma + guaranteed
//   v_cvt_pk_bf16_f32 pairing. Evidence: R9 showed VALU slots convert 1:1
//   to wall time (saturated issue); this removes ~48-160 slots/thread/tile
//   with no register/LDS/sync changes.

constexpr int S_LEN = 2048;
constexpr int DIM   = 64;
constexpr int QT    = 256;
constexpr int KT    = 64;
constexpr int NKT   = S_LEN / KT;   // 32

// tanh(a*x) = 1 - 2/(exp2(2*a*x*log2e)+1); a = 0.3/8 = 0.0375
constexpr float C_EXP2 = 0.10820212528f;

typedef __bf16 bf16_t;
typedef bf16_t bf16x8 __attribute__((ext_vector_type(8)));
typedef float  f32x4  __attribute__((ext_vector_type(4)));
typedef float  f32x2  __attribute__((ext_vector_type(2)));

__device__ inline bf16x8 to_bf8(float4 a, float4 b) {
    bf16x8 v;
    v[0] = (bf16_t)a.x; v[1] = (bf16_t)a.y; v[2] = (bf16_t)a.z; v[3] = (bf16_t)a.w;
    v[4] = (bf16_t)b.x; v[5] = (bf16_t)b.y; v[6] = (bf16_t)b.z; v[7] = (bf16_t)b.w;
    return v;
}

// plain casts -> compiler emits v_cvt_pk_bf16_f32 (m240)
__device__ inline unsigned pack2_bf16(float p0, float p1) {
    union { bf16_t h[2]; unsigned u; } pk;
    pk.h[0] = (bf16_t)p0; pk.h[1] = (bf16_t)p1;
    return pk.u;
}

// tanh of 2 elements in packed-f32 form, returning packed bf16 dword.
// pk_mul + 2x exp2(trans) + pk_add + 2x rcp(trans) + pk_fma + cvt_pk
// = 4 VALU-slot + 4 trans per 2 elems (was ~10 + 4 scalar).
__device__ inline unsigned tanh2_pack(float s0, float s1) {
    f32x2 y; y[0] = s0; y[1] = s1;
    y = y * C_EXP2;                              // v_pk_mul_f32
    f32x2 t;
    t[0] = __builtin_amdgcn_exp2f(y[0]);         // v_exp_f32
    t[1] = __builtin_amdgcn_exp2f(y[1]);
    t = t + 1.0f;                                // v_pk_add_f32
    f32x2 r;
    r[0] = __builtin_amdgcn_rcpf(t[0]);          // v_rcp_f32
    r[1] = __builtin_amdgcn_rcpf(t[1]);
    f32x2 p = r * (-2.0f) + 1.0f;                // v_pk_fma_f32
    return pack2_bf16(p[0], p[1]);               // v_cvt_pk_bf16_f32
}

__global__ __launch_bounds__(512, 4) void tanh_attn_kernel(
    const float* __restrict__ Q, const float* __restrict__ K,
    const float* __restrict__ V, float* __restrict__ O)
{
    const int tid  = threadIdx.x;
    const int lane = tid & 63;
    const int wv   = tid >> 6;          // wave id 0..7 (32 q-rows each)
    const int lr   = lane & 15;
    const int lg   = lane >> 4;

    // XCD-aware bijective swizzle (grid=512, 512%8==0)
    const int nwg = gridDim.x;
    const int bid = (blockIdx.x & 7) * (nwg >> 3) + (blockIdx.x >> 3);
    const int qtile = bid & 7;          // S/QT = 8
    const int bh    = bid >> 3;         // 0..63
    const int base  = bh * (S_LEN * DIM);
    const int q0    = qtile * QT;

    __shared__ bf16_t Ql[QT * DIM];     // 32 KB (Q frags; reused as per-wave P)
    __shared__ bf16_t Kl[2][KT * DIM];  // 2 x 8 KB, [kv][d] swizzled
    __shared__ bf16_t Vt[2][DIM * KT];  // 2 x 8 KB, [d][kv] swizzled (V^T)

    const float* Kb = K + base;
    const float* Vb = V + base;

    // fixed per-thread staging map
    const int sr  = tid >> 3;           // K row 0..63
    const int sc8 = (tid & 7) * 8;      // K col chunk
    const int sd  = tid & 63;           // V d column
    const int skv = (tid >> 6) * 8;     // V kv chunk base

    // ---- issue tile-0 prefetch first (latency overlaps Q staging) ----
    float4 ka, kb2;
    float  vv[8];
    {
        const float* src = Kb + sr * DIM + sc8;
        ka  = *(const float4*)src;
        kb2 = *(const float4*)(src + 4);
        const float* vsrc = Vb + skv * DIM + sd;
        #pragma unroll
        for (int j = 0; j < 8; ++j) vv[j] = vsrc[j * DIM];
    }

    // ---- stage Q tile (f32 -> bf16, XOR swizzle (row&7)<<3) ----
    #pragma unroll
    for (int it = 0; it < 4; ++it) {
        int cid = tid + it * 512;           // 0..2047
        int r   = cid >> 3;
        int c8  = (cid & 7) * 8;
        const float* src = Q + base + (q0 + r) * DIM + c8;
        float4 a = *(const float4*)src;
        float4 b = *(const float4*)(src + 4);
        *(bf16x8*)&Ql[r * DIM + (c8 ^ ((r & 7) << 3))] = to_bf8(a, b);
    }
    __syncthreads();

    // ---- hoist Q fragments (wave's own 32 rows; its P slice = same region,
    //      so no further barrier needed) ----
    bf16x8 qa[2][2];
    #pragma unroll
    for (int rt = 0; rt < 2; ++rt)
        #pragma unroll
        for (int ks = 0; ks < 2; ++ks) {
            int r = wv * 32 + rt * 16 + lr;
            int c = ks * 32 + lg * 8;
            qa[rt][ks] = *(const bf16x8*)&Ql[r * DIM + (c ^ ((r & 7) << 3))];
        }

    // ---- write tile 0 into buffer 0 ----
    {
        *(bf16x8*)&Kl[0][sr * DIM + (sc8 ^ ((sr & 7) << 3))] = to_bf8(ka, kb2);
        bf16x8 v;
        #pragma unroll
        for (int j = 0; j < 8; ++j) v[j] = (bf16_t)vv[j];
        *(bf16x8*)&Vt[0][sd * KT + (skv ^ ((sd & 7) << 3))] = v;
    }

    f32x4 oacc[2][4] = {};
    bf16_t* Pl = Ql + wv * (32 * KT);   // per-wave P slice [32][64] swizzled

    #pragma unroll 2
    for (int kt = 0; kt < NKT; ++kt) {
        const int cur = kt & 1;

        // ONE barrier per tile: publishes buf[cur] writes (end of kt-1) and
        // proves all waves finished reading buf[cur^1].
        __syncthreads();

        // next-tile global loads issued AFTER the barrier; land during compute
        if (kt + 1 < NKT) {
            const int k0n = (kt + 1) * KT;
            const float* src = Kb + (k0n + sr) * DIM + sc8;
            ka  = *(const float4*)src;
            kb2 = *(const float4*)(src + 4);
            const float* vsrc = Vb + (k0n + skv) * DIM + sd;
            #pragma unroll
            for (int j = 0; j < 8; ++j) vv[j] = vsrc[j * DIM];
        }

        const bf16_t* Kc = Kl[cur];
        const bf16_t* Vc = Vt[cur];

        // ---- GEMM1 (swapped): S^T = K · Q^T; D[m=kv][n=q] ----
        f32x4 sacc[2][4] = {};
        __builtin_amdgcn_s_setprio(1);
        #pragma unroll
        for (int ct = 0; ct < 4; ++ct) {
            int r = ct * 16 + lr;           // kv
            bf16x8 kf0 = *(const bf16x8*)&Kc[r * DIM + ((lg * 8)      ^ ((r & 7) << 3))];
            bf16x8 kf1 = *(const bf16x8*)&Kc[r * DIM + ((32 + lg * 8) ^ ((r & 7) << 3))];
            #pragma unroll
            for (int rt = 0; rt < 2; ++rt) {
                sacc[rt][ct] = __builtin_amdgcn_mfma_f32_16x16x32_bf16(kf0, qa[rt][0], sacc[rt][ct], 0, 0, 0);
                sacc[rt][ct] = __builtin_amdgcn_mfma_f32_16x16x32_bf16(kf1, qa[rt][1], sacc[rt][ct], 0, 0, 0);
            }
        }
        __builtin_amdgcn_s_setprio(0);

        // ---- packed tanh + packed P store (lane: q=rt*16+lr, kv=ct*16+lg*4+j)
        #pragma unroll
        for (int rt = 0; rt < 2; ++rt)
            #pragma unroll
            for (int ct = 0; ct < 4; ++ct) {
                union { unsigned u[2]; } pw;
                pw.u[0] = tanh2_pack(sacc[rt][ct][0], sacc[rt][ct][1]);
                pw.u[1] = tanh2_pack(sacc[rt][ct][2], sacc[rt][ct][3]);
                int q  = rt * 16 + lr;
                int c0 = ct * 16 + lg * 4;
                *(uint2*)&Pl[q * KT + (c0 ^ ((q & 7) << 3))] =
                    make_uint2(pw.u[0], pw.u[1]);
            }

        // ---- P A-fragments (same-wave LDS slice, no barrier) ----
        bf16x8 pa[2][2];
        #pragma unroll
        for (int rt = 0; rt < 2; ++rt)
            #pragma unroll
            for (int ks = 0; ks < 2; ++ks) {
                int r = rt * 16 + lr;
                pa[rt][ks] = *(const bf16x8*)&Pl[r * KT + ((ks * 32 + lg * 8) ^ ((r & 7) << 3))];
            }

        // ---- GEMM2: O += P · V ----
        __builtin_amdgcn_s_setprio(1);
        #pragma unroll
        for (int dt = 0; dt < 4; ++dt) {
            int d = dt * 16 + lr;
            bf16x8 vf0 = *(const bf16x8*)&Vc[d * KT + ((lg * 8)      ^ ((d & 7) << 3))];
            bf16x8 vf1 = *(const bf16x8*)&Vc[d * KT + ((32 + lg * 8) ^ ((d & 7) << 3))];
            #pragma unroll
            for (int rt = 0; rt < 2; ++rt) {
                oacc[rt][dt] = __builtin_amdgcn_mfma_f32_16x16x32_bf16(pa[rt][0], vf0, oacc[rt][dt], 0, 0, 0);
                oacc[rt][dt] = __builtin_amdgcn_mfma_f32_16x16x32_bf16(pa[rt][1], vf1, oacc[rt][dt], 0, 0, 0);
            }
        }
        __builtin_amdgcn_s_setprio(0);

        // ---- write next tile into the other buffer (loads landed during
        //      compute; next barrier publishes these writes) ----
        if (kt + 1 < NKT) {
            const int nxt = cur ^ 1;
            *(bf16x8*)&Kl[nxt][sr * DIM + (sc8 ^ ((sr & 7) << 3))] = to_bf8(ka, kb2);
            bf16x8 v;
            #pragma unroll
            for (int j = 0; j < 8; ++j) v[j] = (bf16_t)vv[j];
            *(bf16x8*)&Vt[nxt][sd * KT + (skv ^ ((sd & 7) << 3))] = v;
        }
    }

    // ---- epilogue: write O (f32) ----
    #pragma unroll
    for (int rt = 0; rt < 2; ++rt)
        #pragma unroll
        for (int dt = 0; dt < 4; ++dt)
            #pragma unroll
            for (int j = 0; j < 4; ++j) {
                int q = q0 + wv * 32 + rt * 16 + lg * 4 + j;
                int d = dt * 16 + lr;
                O[base + q * DIM + d] = oacc[rt][dt][j];
            }
}

extern "C" void kernel_launch(void* const* d_in, const int* in_sizes, int n_in,
                              void* d_out, int out_size, void* d_ws, size_t ws_size,
                              hipStream_t stream) {
    const float* Q = (const float*)d_in[0];
    const float* K = (const float*)d_in[1];
    const float* V = (const float*)d_in[2];
    float* O = (float*)d_out;
    dim3 grid(64 * (S_LEN / QT));   // 512 blocks
    dim3 block(512);
    hipLaunchKernelGGL(tanh_attn_kernel, grid, block, 0, stream, Q, K, V, O);
}

// Round 12
// 108.657 us; speedup vs baseline: 1.1956x; 1.0053x over previous
//
#include <hip/hip_runtime.h>

// Problem: B=4, H=16, S=2048, D=64
//   scores = Q K^T / 8 ; attn = tanh(0.3*scores) ; out = attn V   (mask unused)
// Round 12: WIDEN THE SYNC PERIOD. Evidence R5..R11: no pipe >45% busy;
//   wall = sum of lockstep phase windows re-synced by the per-tile barrier.
//   Barrier every 2 TILES (quad-buffered K/V): waves drift out of phase
//   within the window so tanh/LDS/MFMA bursts of different waves overlap.
//   Q frags in registers (direct global load), P slice 16 rows reused per
//   rt-half. LDS = 32K(K) + 32K(V) + 16K(P) = 80 KB -> 2 blocks = 160 KB/CU.

constexpr int S_LEN = 2048;
constexpr int DIM   = 64;
constexpr int QT    = 256;
constexpr int KT    = 64;
constexpr int NKT   = S_LEN / KT;   // 32
constexpr int NW    = NKT / 2;      // 16 windows

// tanh(a*x) = 1 - 2/(exp2(2*a*x*log2e)+1); a = 0.3/8 = 0.0375
constexpr float C_EXP2 = 0.10820212528f;

typedef __bf16 bf16_t;
typedef bf16_t bf16x4 __attribute__((ext_vector_type(4)));
typedef bf16_t bf16x8 __attribute__((ext_vector_type(8)));
typedef float  f32x4  __attribute__((ext_vector_type(4)));

__device__ inline bf16x8 to_bf8(float4 a, float4 b) {
    bf16x8 v;
    v[0] = (bf16_t)a.x; v[1] = (bf16_t)a.y; v[2] = (bf16_t)a.z; v[3] = (bf16_t)a.w;
    v[4] = (bf16_t)b.x; v[5] = (bf16_t)b.y; v[6] = (bf16_t)b.z; v[7] = (bf16_t)b.w;
    return v;
}

__device__ inline float tanh_fast(float s) {
    float t = __builtin_amdgcn_exp2f(s * C_EXP2);
    return 1.0f - 2.0f * __builtin_amdgcn_rcpf(t + 1.0f);
}

__global__ __launch_bounds__(512, 4) void tanh_attn_kernel(
    const float* __restrict__ Q, const float* __restrict__ K,
    const float* __restrict__ V, float* __restrict__ O)
{
    const int tid  = threadIdx.x;
    const int lane = tid & 63;
    const int wv   = tid >> 6;          // wave id 0..7 (32 q-rows each)
    const int lr   = lane & 15;
    const int lg   = lane >> 4;

    // XCD-aware bijective swizzle (grid=512, 512%8==0)
    const int nwg = gridDim.x;
    const int bid = (blockIdx.x & 7) * (nwg >> 3) + (blockIdx.x >> 3);
    const int qtile = bid & 7;          // S/QT = 8
    const int bh    = bid >> 3;         // 0..63
    const int base  = bh * (S_LEN * DIM);
    const int q0    = qtile * QT;

    __shared__ bf16_t Kl[4][KT * DIM];  // 4 x 8 KB, [kv][d] swizzled
    __shared__ bf16_t Vt[4][DIM * KT];  // 4 x 8 KB, [d][kv] swizzled (V^T)
    __shared__ bf16_t Pl[8][16 * KT];   // 16 KB: per-wave 16-row P slice

    const float* Kb = K + base;
    const float* Vb = V + base;

    // fixed per-thread staging map
    const int sr  = tid >> 3;           // K row 0..63
    const int sc8 = (tid & 7) * 8;      // K col chunk
    const int sd  = tid & 63;           // V d column
    const int skv = (tid >> 6) * 8;     // V kv chunk base

    float4 ka, kb2;
    float  vv[8];

    // ---- prologue: stage tiles 0 and 1; Q fragments direct from global ----
    {
        const float* src = Kb + sr * DIM + sc8;
        ka  = *(const float4*)src;
        kb2 = *(const float4*)(src + 4);
        const float* vsrc = Vb + skv * DIM + sd;
        #pragma unroll
        for (int j = 0; j < 8; ++j) vv[j] = vsrc[j * DIM];
    }

    bf16x8 qa[2][2];
    #pragma unroll
    for (int rt = 0; rt < 2; ++rt)
        #pragma unroll
        for (int ks = 0; ks < 2; ++ks) {
            const float* src = Q + base + (q0 + wv * 32 + rt * 16 + lr) * DIM
                               + ks * 32 + lg * 8;
            float4 a = *(const float4*)src;
            float4 b = *(const float4*)(src + 4);
            qa[rt][ks] = to_bf8(a, b);
        }

    {   // write tile 0
        *(bf16x8*)&Kl[0][sr * DIM + (sc8 ^ ((sr & 7) << 3))] = to_bf8(ka, kb2);
        bf16x8 v;
        #pragma unroll
        for (int j = 0; j < 8; ++j) v[j] = (bf16_t)vv[j];
        *(bf16x8*)&Vt[0][sd * KT + (skv ^ ((sd & 7) << 3))] = v;
    }
    {   // load + write tile 1
        const float* src = Kb + (KT + sr) * DIM + sc8;
        ka  = *(const float4*)src;
        kb2 = *(const float4*)(src + 4);
        const float* vsrc = Vb + (KT + skv) * DIM + sd;
        #pragma unroll
        for (int j = 0; j < 8; ++j) vv[j] = vsrc[j * DIM];
        *(bf16x8*)&Kl[1][sr * DIM + (sc8 ^ ((sr & 7) << 3))] = to_bf8(ka, kb2);
        bf16x8 v;
        #pragma unroll
        for (int j = 0; j < 8; ++j) v[j] = (bf16_t)vv[j];
        *(bf16x8*)&Vt[1][sd * KT + (skv ^ ((sd & 7) << 3))] = v;
    }

    f32x4 oacc[2][4] = {};
    bf16_t* Pw = &Pl[wv][0];            // this wave's 16-row P slice

    // one tile: G1 -> tanh -> P(roundtrip per rt-half) -> G2
    auto compute = [&](const bf16_t* __restrict__ Kc,
                       const bf16_t* __restrict__ Vc) {
        // GEMM1 (swapped): S^T = K · Q^T; D[m=kv][n=q]
        f32x4 sacc[2][4] = {};
        __builtin_amdgcn_s_setprio(1);
        #pragma unroll
        for (int ct = 0; ct < 4; ++ct) {
            int r = ct * 16 + lr;       // kv
            bf16x8 kf0 = *(const bf16x8*)&Kc[r * DIM + ((lg * 8)      ^ ((r & 7) << 3))];
            bf16x8 kf1 = *(const bf16x8*)&Kc[r * DIM + ((32 + lg * 8) ^ ((r & 7) << 3))];
            #pragma unroll
            for (int rt = 0; rt < 2; ++rt) {
                sacc[rt][ct] = __builtin_amdgcn_mfma_f32_16x16x32_bf16(kf0, qa[rt][0], sacc[rt][ct], 0, 0, 0);
                sacc[rt][ct] = __builtin_amdgcn_mfma_f32_16x16x32_bf16(kf1, qa[rt][1], sacc[rt][ct], 0, 0, 0);
            }
        }
        __builtin_amdgcn_s_setprio(0);

        // tanh + P roundtrip, one rt-half at a time (16-row slice reused)
        bf16x8 pa[2][2];
        #pragma unroll
        for (int rt = 0; rt < 2; ++rt) {
            #pragma unroll
            for (int ct = 0; ct < 4; ++ct) {
                bf16x4 p4;
                #pragma unroll
                for (int j = 0; j < 4; ++j)
                    p4[j] = (bf16_t)tanh_fast(sacc[rt][ct][j]);
                int c0 = ct * 16 + lg * 4;
                *(bf16x4*)&Pw[lr * KT + (c0 ^ ((lr & 7) << 3))] = p4;
            }
            #pragma unroll
            for (int ks = 0; ks < 2; ++ks)
                pa[rt][ks] = *(const bf16x8*)&Pw[lr * KT + ((ks * 32 + lg * 8) ^ ((lr & 7) << 3))];
        }

        // GEMM2: O += P · V
        __builtin_amdgcn_s_setprio(1);
        #pragma unroll
        for (int dt = 0; dt < 4; ++dt) {
            int d = dt * 16 + lr;
            bf16x8 vf0 = *(const bf16x8*)&Vc[d * KT + ((lg * 8)      ^ ((d & 7) << 3))];
            bf16x8 vf1 = *(const bf16x8*)&Vc[d * KT + ((32 + lg * 8) ^ ((d & 7) << 3))];
            #pragma unroll
            for (int rt = 0; rt < 2; ++rt) {
                oacc[rt][dt] = __builtin_amdgcn_mfma_f32_16x16x32_bf16(pa[rt][0], vf0, oacc[rt][dt], 0, 0, 0);
                oacc[rt][dt] = __builtin_amdgcn_mfma_f32_16x16x32_bf16(pa[rt][1], vf1, oacc[rt][dt], 0, 0, 0);
            }
        }
        __builtin_amdgcn_s_setprio(0);
    };

    for (int w = 0; w < NW; ++w) {
        const int p  = (w & 1) * 2;     // buffers read this window
        const int np = p ^ 2;           // buffers written this window
        const int t2 = 2 * w + 2, t3 = 2 * w + 3;

        // barrier: publishes bufs[np..np+1] writes from prev window, and
        // proves all waves finished reading them (they were read 2 windows ago)
        __syncthreads();

        // issue loads for tile t2 (land during tile-A compute)
        if (t2 < NKT) {
            const float* src = Kb + (t2 * KT + sr) * DIM + sc8;
            ka  = *(const float4*)src;
            kb2 = *(const float4*)(src + 4);
            const float* vsrc = Vb + (t2 * KT + skv) * DIM + sd;
            #pragma unroll
            for (int j = 0; j < 8; ++j) vv[j] = vsrc[j * DIM];
        }

        compute(Kl[p], Vt[p]);          // tile 2w

        // write t2 (nobody reads np this window), then issue t3 loads
        if (t2 < NKT) {
            *(bf16x8*)&Kl[np][sr * DIM + (sc8 ^ ((sr & 7) << 3))] = to_bf8(ka, kb2);
            bf16x8 v;
            #pragma unroll
            for (int j = 0; j < 8; ++j) v[j] = (bf16_t)vv[j];
            *(bf16x8*)&Vt[np][sd * KT + (skv ^ ((sd & 7) << 3))] = v;
        }
        if (t3 < NKT) {
            const float* src = Kb + (t3 * KT + sr) * DIM + sc8;
            ka  = *(const float4*)src;
            kb2 = *(const float4*)(src + 4);
            const float* vsrc = Vb + (t3 * KT + skv) * DIM + sd;
            #pragma unroll
            for (int j = 0; j < 8; ++j) vv[j] = vsrc[j * DIM];
        }

        compute(Kl[p + 1], Vt[p + 1]);  // tile 2w+1

        if (t3 < NKT) {
            *(bf16x8*)&Kl[np + 1][sr * DIM + (sc8 ^ ((sr & 7) << 3))] = to_bf8(ka, kb2);
            bf16x8 v;
            #pragma unroll
            for (int j = 0; j < 8; ++j) v[j] = (bf16_t)vv[j];
            *(bf16x8*)&Vt[np + 1][sd * KT + (skv ^ ((sd & 7) << 3))] = v;
        }
    }

    // ---- epilogue: write O (f32) ----
    #pragma unroll
    for (int rt = 0; rt < 2; ++rt)
        #pragma unroll
        for (int dt = 0; dt < 4; ++dt)
            #pragma unroll
            for (int j = 0; j < 4; ++j) {
                int q = q0 + wv * 32 + rt * 16 + lg * 4 + j;
                int d = dt * 16 + lr;
                O[base + q * DIM + d] = oacc[rt][dt][j];
            }
}

extern "C" void kernel_launch(void* const* d_in, const int* in_sizes, int n_in,
                              void* d_out, int out_size, void* d_ws, size_t ws_size,
                              hipStream_t stream) {
    const float* Q = (const float*)d_in[0];
    const float* K = (const float*)d_in[1];
    const float* V = (const float*)d_in[2];
    float* O = (float*)d_out;
    dim3 grid(64 * (S_LEN / QT));   // 512 blocks
    dim3 block(512);
    hipLaunchKernelGGL(tanh_attn_kernel, grid, block, 0, stream, Q, K, V, O);
}